// Round 1
// baseline (49587.338 us; speedup 1.0000x reference)
//
#include <hip/hip_runtime.h>
#include <cstdint>
#include <cstddef>

// ============================================================================
// Persistent fused 2-layer LSTM + FC for MI355X (gfx950).
// Round 1: fp32 VALU baseline (no MFMA yet) to validate the architecture:
//   - 256 blocks x 256 threads, 1 block/CU (139 KB LDS forces it -> all blocks
//     co-resident, hand-rolled grid barrier is safe without cooperative API).
//   - Wave w of block bk owns hidden unit jw = bk*4+w: its 4 gate rows of
//     W_ih/W_hh live in VGPRs (k-distributed across 64 lanes), cell state c
//     lives in a lane register, never touches memory.
//   - Per step: h_{t-1} staged global->LDS (coalesced), dot products
//     accumulated per-lane, 64-lane shfl_xor butterfly reduce, gate math,
//     scatter-store h_t, two-level grid barrier (agent-scope atomics+fences).
//   - Layer 1 fuses its input GEMM (K=1024 h1 + 1024 h2 = 2048) and the final
//     FC (h2[t-1] already staged in LDS; block owns 2 of 512 output cols).
// ============================================================================

#define NBLK 256
#define NTHR 256

namespace {
constexpr int kB = 32, kT = 512, kI = 256, kH = 1024, kO = 512, kTR = 500;
// workspace layout (floats):
constexpr size_t kBarFloats = 2048;                       // 8 KB barrier region
constexpr size_t kH1Off = kBarFloats;                     // h1: [T+1][B][H]
constexpr size_t kH1Len = (size_t)(kT + 1) * kB * kH;
constexpr size_t kH2Off = kH1Off + kH1Len;                // h2: [2][B][H] ping-pong
// total ws need: (2048 + 513*32768 + 2*32768)*4 B ~= 67.5 MB
constexpr int kLdsFloats = 32768 + 2048;                  // h-stage + Wfc rows
constexpr int kLdsBytes = kLdsFloats * 4;                 // 139264 B
}

// ---------------------------------------------------------------------------
// Two-level sense-reversing grid barrier.
// bar layout (unsigned words, padded 128 B apart to avoid one-line contention):
//   [i*32] i=0..31 : leaf counters (8 blocks each)
//   [1024]         : root counter
//   [1056]         : generation flag
// Release chain: leaf inc (acq_rel) -> root inc (acq_rel) -> gen store
// (release); spinners acquire via fence. __threadfence() at agent scope emits
// the L2 writeback/invalidate needed for cross-XCD visibility of the plain
// h stores (per-XCD L2s are not coherent).
// ---------------------------------------------------------------------------
__device__ __forceinline__ void grid_barrier(unsigned* bar) {
  __syncthreads();                      // drains vmcnt: all block stores at L2
  if (threadIdx.x == 0) {
    __threadfence();                    // agent release: L2 -> LLC
    unsigned gen = __hip_atomic_load(&bar[1056], __ATOMIC_RELAXED,
                                     __HIP_MEMORY_SCOPE_AGENT);
    const int leaf = (int)(blockIdx.x & 31);
    unsigned prev = __hip_atomic_fetch_add(&bar[leaf * 32], 1u,
                                           __ATOMIC_ACQ_REL,
                                           __HIP_MEMORY_SCOPE_AGENT);
    if (prev == 7u) {                   // last of this leaf's 8 blocks
      __hip_atomic_store(&bar[leaf * 32], 0u, __ATOMIC_RELAXED,
                         __HIP_MEMORY_SCOPE_AGENT);
      unsigned r = __hip_atomic_fetch_add(&bar[1024], 1u, __ATOMIC_ACQ_REL,
                                          __HIP_MEMORY_SCOPE_AGENT);
      if (r == 31u) {                   // last leaf
        __hip_atomic_store(&bar[1024], 0u, __ATOMIC_RELAXED,
                           __HIP_MEMORY_SCOPE_AGENT);
        __hip_atomic_store(&bar[1056], gen + 1u, __ATOMIC_RELEASE,
                           __HIP_MEMORY_SCOPE_AGENT);
      }
    }
    while (__hip_atomic_load(&bar[1056], __ATOMIC_RELAXED,
                             __HIP_MEMORY_SCOPE_AGENT) == gen) {
      __builtin_amdgcn_s_sleep(1);
    }
    __threadfence();                    // agent acquire: inv L1/L2
  }
  __syncthreads();
}

// full 64-lane sum; every lane ends with the total
__device__ __forceinline__ float wave_sum(float x) {
  x += __shfl_xor(x, 1);
  x += __shfl_xor(x, 2);
  x += __shfl_xor(x, 4);
  x += __shfl_xor(x, 8);
  x += __shfl_xor(x, 16);
  x += __shfl_xor(x, 32);
  return x;
}

__device__ __forceinline__ float sigmoid_f(float x) {
  return __builtin_amdgcn_rcpf(1.f + __expf(-x));
}
__device__ __forceinline__ float tanh_f(float x) {
  // 1 - 2/(1+e^{2x}) : exact at +-inf (rcp(inf)=0), no NaNs
  return 1.f - 2.f * __builtin_amdgcn_rcpf(1.f + __expf(2.f * x));
}

__global__ void __launch_bounds__(NTHR, 1) lstm_init_kernel(float* ws) {
  const size_t idx = (size_t)blockIdx.x * blockDim.x + threadIdx.x;
  if (idx < kBarFloats) ((unsigned*)ws)[idx] = 0u;
  if (idx < (size_t)kB * kH) {
    ws[kH1Off + idx] = 0.f;             // h1 state at tau=0
    ws[kH2Off + idx] = 0.f;             // h2 slot 0 (tau=0)
  }
}

__global__ void __launch_bounds__(NTHR, 1) lstm_persist_kernel(
    const float* __restrict__ x,
    const float* __restrict__ Wih0, const float* __restrict__ Whh0,
    const float* __restrict__ bih0, const float* __restrict__ bhh0,
    const float* __restrict__ Wih1, const float* __restrict__ Whh1,
    const float* __restrict__ bih1, const float* __restrict__ bhh1,
    const float* __restrict__ Wfc, const float* __restrict__ bfc,
    float* __restrict__ out, float* __restrict__ ws) {
  const int tid = threadIdx.x;
  const int bk = blockIdx.x;
  const int w = tid >> 6;               // wave 0..3
  const int lane = tid & 63;
  const int jw = bk * 4 + w;            // owned hidden unit (0..1023)
  unsigned* bar = (unsigned*)ws;
  float* h1 = ws + kH1Off;              // [T+1][B][H]
  float* h2 = ws + kH2Off;              // [2][B][H]
  extern __shared__ float lds[];        // [0..32767] stage, [32768..34815] Wfc

  // ======================= Phase 0: layer 0 =======================
  {
    float wih[4][4], whh[4][16], bias[4];
#pragma unroll
    for (int g = 0; g < 4; ++g) {
#pragma unroll
      for (int c = 0; c < 4; ++c)
        wih[g][c] = Wih0[(size_t)(g * kH + jw) * kI + c * 64 + lane];
#pragma unroll
      for (int c = 0; c < 16; ++c)
        whh[g][c] = Whh0[(size_t)(g * kH + jw) * kH + c * 64 + lane];
      bias[g] = bih0[g * kH + jw] + bhh0[g * kH + jw];
    }
    float creg = 0.f;                   // c for (b=lane, jw), lanes 0..31

    for (int t = 0; t < kT; ++t) {
      // stage h1[t] (32x1024 fp32 = 128 KB) into LDS, coalesced float4
      {
        const float4* s4 = (const float4*)(h1 + (size_t)t * (kB * kH));
        float4* d4 = (float4*)lds;
#pragma unroll
        for (int i = 0; i < (kB * kH / 4) / NTHR; ++i)
          d4[i * NTHR + tid] = s4[i * NTHR + tid];
      }
      __syncthreads();

      float myg0 = 0.f, myg1 = 0.f, myg2 = 0.f, myg3 = 0.f;
      // prefetch x for b=0
      float xv0, xv1, xv2, xv3;
      {
        const float* xp = x + (size_t)t * kI + lane;   // b=0
        xv0 = xp[0]; xv1 = xp[64]; xv2 = xp[128]; xv3 = xp[192];
      }
      for (int b = 0; b < kB; ++b) {
        float a0 = 0.f, a1 = 0.f, a2 = 0.f, a3 = 0.f;
        // recurrent part, K=1024 from LDS (lane-contiguous, conflict-free)
#pragma unroll
        for (int c = 0; c < 16; ++c) {
          const float hv = lds[b * kH + c * 64 + lane];
          a0 = fmaf(hv, whh[0][c], a0);
          a1 = fmaf(hv, whh[1][c], a1);
          a2 = fmaf(hv, whh[2][c], a2);
          a3 = fmaf(hv, whh[3][c], a3);
        }
        // prefetch next b's x while x-part FMAs run
        float nx0 = 0.f, nx1 = 0.f, nx2 = 0.f, nx3 = 0.f;
        if (b + 1 < kB) {
          const float* xp = x + ((size_t)(b + 1) * kT + t) * kI + lane;
          nx0 = xp[0]; nx1 = xp[64]; nx2 = xp[128]; nx3 = xp[192];
        }
        // input part, K=256
        a0 = fmaf(xv0, wih[0][0], fmaf(xv1, wih[0][1],
             fmaf(xv2, wih[0][2], fmaf(xv3, wih[0][3], a0))));
        a1 = fmaf(xv0, wih[1][0], fmaf(xv1, wih[1][1],
             fmaf(xv2, wih[1][2], fmaf(xv3, wih[1][3], a1))));
        a2 = fmaf(xv0, wih[2][0], fmaf(xv1, wih[2][1],
             fmaf(xv2, wih[2][2], fmaf(xv3, wih[2][3], a2))));
        a3 = fmaf(xv0, wih[3][0], fmaf(xv1, wih[3][1],
             fmaf(xv2, wih[3][2], fmaf(xv3, wih[3][3], a3))));
        xv0 = nx0; xv1 = nx1; xv2 = nx2; xv3 = nx3;
        // reduce across 64 lanes; keep result in lane b
        a0 = wave_sum(a0); a1 = wave_sum(a1);
        a2 = wave_sum(a2); a3 = wave_sum(a3);
        if (lane == b) { myg0 = a0; myg1 = a1; myg2 = a2; myg3 = a3; }
      }
      // gate math: lane b holds gates for (b, jw). PyTorch order i,f,g,o.
      const float gi = sigmoid_f(myg0 + bias[0]);
      const float gf = sigmoid_f(myg1 + bias[1]);
      const float gg = tanh_f(myg2 + bias[2]);
      const float go = sigmoid_f(myg3 + bias[3]);
      creg = gf * creg + gi * gg;
      const float hnew = go * tanh_f(creg);
      if (lane < kB)
        h1[((size_t)(t + 1) * kB + lane) * kH + jw] = hnew;
      grid_barrier(bar);
    }
  }

  // ================= Phase 1: layer 1 + fused FC =================
  {
    float wih[4][16], whh[4][16], bias[4];
#pragma unroll
    for (int g = 0; g < 4; ++g) {
#pragma unroll
      for (int c = 0; c < 16; ++c) {
        wih[g][c] = Wih1[(size_t)(g * kH + jw) * kH + c * 64 + lane];
        whh[g][c] = Whh1[(size_t)(g * kH + jw) * kH + c * 64 + lane];
      }
      bias[g] = bih1[g * kH + jw] + bhh1[g * kH + jw];
    }
    // stage this block's 2 Wfc rows (o = bk*2, bk*2+1) once
    for (int i = tid; i < 2 * kH; i += NTHR)
      lds[32768 + i] = Wfc[(size_t)(bk * 2) * kH + i];
    const int o_loc = w & 1;
    const int b_sub = (w >> 1) * 8;     // this wave's b-offset within a group
    const float bfco = bfc[bk * 2 + o_loc];
    float creg = 0.f;

    for (int t = 0; t < kT; ++t) {
      float myg0 = 0.f, myg1 = 0.f, myg2 = 0.f, myg3 = 0.f;
      // process b in 2 groups of 16 so h1-input and h2-recurrent halves
      // both fit in the 128 KB stage buffer
      for (int grp = 0; grp < 2; ++grp) {
        __syncthreads();                // previous group's reads done
        {
          const float4* s1 =
              (const float4*)(h1 + ((size_t)(t + 1) * kB + grp * 16) * kH);
          const float4* s2 =
              (const float4*)(h2 + ((size_t)(t & 1) * kB + grp * 16) * kH);
          float4* d1 = (float4*)lds;
          float4* d2 = (float4*)(lds + 16384);
#pragma unroll
          for (int i = 0; i < 4096 / NTHR; ++i) {
            d1[i * NTHR + tid] = s1[i * NTHR + tid];
            d2[i * NTHR + tid] = s2[i * NTHR + tid];
          }
        }
        __syncthreads();
        for (int b2 = 0; b2 < 16; ++b2) {
          const int b = grp * 16 + b2;
          float a0 = 0.f, a1 = 0.f, a2 = 0.f, a3 = 0.f;
#pragma unroll
          for (int c = 0; c < 16; ++c) {          // input part: h1[t+1]
            const float hv = lds[b2 * kH + c * 64 + lane];
            a0 = fmaf(hv, wih[0][c], a0);
            a1 = fmaf(hv, wih[1][c], a1);
            a2 = fmaf(hv, wih[2][c], a2);
            a3 = fmaf(hv, wih[3][c], a3);
          }
#pragma unroll
          for (int c = 0; c < 16; ++c) {          // recurrent part: h2[t]
            const float gv = lds[16384 + b2 * kH + c * 64 + lane];
            a0 = fmaf(gv, whh[0][c], a0);
            a1 = fmaf(gv, whh[1][c], a1);
            a2 = fmaf(gv, whh[2][c], a2);
            a3 = fmaf(gv, whh[3][c], a3);
          }
          a0 = wave_sum(a0); a1 = wave_sum(a1);
          a2 = wave_sum(a2); a3 = wave_sum(a3);
          if (lane == b) { myg0 = a0; myg1 = a1; myg2 = a2; myg3 = a3; }
        }
        // fused FC: staged h2[t] is the layer-2 output at time t-1
        if (t >= 1 && t <= kTR) {
          float wf[16];
#pragma unroll
          for (int c = 0; c < 16; ++c)
            wf[c] = lds[32768 + o_loc * kH + c * 64 + lane];
          float myout = 0.f;
          for (int b2 = 0; b2 < 8; ++b2) {
            const int bb = b_sub + b2;            // within group
            float f = 0.f;
#pragma unroll
            for (int c = 0; c < 16; ++c)
              f = fmaf(lds[16384 + bb * kH + c * 64 + lane], wf[c], f);
            f = wave_sum(f);
            if (lane == b2) myout = f;
          }
          if (lane < 8) {
            const int b = grp * 16 + b_sub + lane;
            out[((size_t)b * kTR + (t - 1)) * kO + bk * 2 + o_loc] =
                myout + bfco;
          }
        }
      }
      const float gi = sigmoid_f(myg0 + bias[0]);
      const float gf = sigmoid_f(myg1 + bias[1]);
      const float gg = tanh_f(myg2 + bias[2]);
      const float go = sigmoid_f(myg3 + bias[3]);
      creg = gf * creg + gi * gg;
      const float hnew = go * tanh_f(creg);
      if (lane < kB)
        h2[((size_t)((t + 1) & 1) * kB + lane) * kH + jw] = hnew;
      grid_barrier(bar);
    }
  }
}

extern "C" void kernel_launch(void* const* d_in, const int* in_sizes, int n_in,
                              void* d_out, int out_size, void* d_ws,
                              size_t ws_size, hipStream_t stream) {
  const float* x    = (const float*)d_in[0];
  const float* Wih0 = (const float*)d_in[1];
  const float* Whh0 = (const float*)d_in[2];
  const float* bih0 = (const float*)d_in[3];
  const float* bhh0 = (const float*)d_in[4];
  const float* Wih1 = (const float*)d_in[5];
  const float* Whh1 = (const float*)d_in[6];
  const float* bih1 = (const float*)d_in[7];
  const float* bhh1 = (const float*)d_in[8];
  const float* Wfc  = (const float*)d_in[9];
  const float* bfc  = (const float*)d_in[10];
  float* out = (float*)d_out;
  float* ws  = (float*)d_ws;

  // allow >64 KB dynamic LDS (139264 B); harmless if already permitted
  (void)hipFuncSetAttribute((const void*)lstm_persist_kernel,
                            hipFuncAttributeMaxDynamicSharedMemorySize,
                            kLdsBytes);

  // re-init barrier + zero h1[0]/h2[0] every call (ws is re-poisoned 0xAA)
  hipLaunchKernelGGL(lstm_init_kernel, dim3(128), dim3(NTHR), 0, stream, ws);
  hipLaunchKernelGGL(lstm_persist_kernel, dim3(NBLK), dim3(NTHR), kLdsBytes,
                     stream, x, Wih0, Whh0, bih0, bhh0, Wih1, Whh1, bih1,
                     bhh1, Wfc, bfc, out, ws);
}

// Round 2
// 28384.821 us; speedup vs baseline: 1.7470x; 1.7470x over previous
//
#include <hip/hip_runtime.h>
#include <cstdint>
#include <cstddef>

// ============================================================================
// Persistent fused 2-layer LSTM + FC for MI355X (gfx950).
// Round 2: same compute structure as R1 (fp32 VALU, weights in VGPRs), but the
// cross-block synchronization is rearchitected:
//   - R1 spent ~90% of each step in sync (VALUBusy 10.8%): serialized atomic
//     tree + __threadfence (= full L2 wb/inv per block per step).
//   - Now: all mutable cross-block data (h1/h2) moves via agent-scope RELAXED
//     atomics (sc1 write-through stores, sc1 LLC-direct loads) -> no cache
//     invalidates needed, no false-sharing RFO on the h scatter.
//   - Grid barrier: parallel per-block flag stores (monotonic step numbers,
//     no reset) + one sweeper wave in block 0 that polls all 256 flags and
//     publishes a generation word. No serialized fetch_add chains.
//   - 256 blocks x 256 threads, 1 block/CU (139 KB LDS) -> co-residency is
//     structural; barrier cannot deadlock.
// ============================================================================

#define NBLK 256
#define NTHR 256

namespace {
constexpr int kB = 32, kT = 512, kI = 256, kH = 1024, kO = 512, kTR = 500;
constexpr int kSteps = 501;                               // only t<=500 needed
// workspace layout (floats):
constexpr size_t kBarFloats = 2048;                       // flags[256]+gen
constexpr size_t kH1Off = kBarFloats;                     // h1: [T+1][B][H]
constexpr size_t kH1Len = (size_t)(kT + 1) * kB * kH;
constexpr size_t kH2Off = kH1Off + kH1Len;                // h2: [2][B][H]
constexpr int kLdsFloats = 32768 + 2048;                  // h-stage + Wfc rows
constexpr int kLdsBytes = kLdsFloats * 4;                 // 139264 B
constexpr int kGenWord = 320;                             // gen flag (own line)
}

typedef unsigned long long u64;

// ---------------------------------------------------------------------------
// Grid barrier, generation-counting (steps are globally monotonic 1..1002):
//   every block:  flags[bk] = step   (RELEASE, agent: drains vmcnt, sc1 store)
//   block 0 w0 :  sweep flags[0..255] (4 relaxed sc1 loads/lane) until all
//                 >= step, then flags[kGenWord] = step (RELEASE)
//   others     :  spin on flags[kGenWord] (relaxed sc1), backoff s_sleep
//   everyone   :  one ACQUIRE load of gen as the formal ordering point
// No __threadfence -> no L2 writeback/invalidate storms.
// ---------------------------------------------------------------------------
__device__ __forceinline__ void grid_barrier(unsigned* flags, unsigned step) {
  __syncthreads();                      // all waves' stores drained (vmcnt)
  const int tid = threadIdx.x;
  if (blockIdx.x == 0) {
    if (tid < 64) {
      if (tid == 0)
        __hip_atomic_store(&flags[0], step, __ATOMIC_RELEASE,
                           __HIP_MEMORY_SCOPE_AGENT);
      const int l4 = tid << 2;
      bool done;
      do {
        unsigned ok = 1u;
#pragma unroll
        for (int k = 0; k < 4; ++k)
          ok &= (unsigned)(__hip_atomic_load(&flags[l4 + k], __ATOMIC_RELAXED,
                                             __HIP_MEMORY_SCOPE_AGENT) >= step);
        done = __all((int)ok);
        if (!done) __builtin_amdgcn_s_sleep(2);
      } while (!done);
      if (tid == 0)
        __hip_atomic_store(&flags[kGenWord], step, __ATOMIC_RELEASE,
                           __HIP_MEMORY_SCOPE_AGENT);
    }
  } else if (tid == 0) {
    __hip_atomic_store(&flags[blockIdx.x], step, __ATOMIC_RELEASE,
                       __HIP_MEMORY_SCOPE_AGENT);
    while (__hip_atomic_load(&flags[kGenWord], __ATOMIC_RELAXED,
                             __HIP_MEMORY_SCOPE_AGENT) < step)
      __builtin_amdgcn_s_sleep(8);
  }
  if (tid == 0)
    (void)__hip_atomic_load(&flags[kGenWord], __ATOMIC_ACQUIRE,
                            __HIP_MEMORY_SCOPE_AGENT);
  __syncthreads();
}

__device__ __forceinline__ float wave_sum(float x) {
  x += __shfl_xor(x, 1);
  x += __shfl_xor(x, 2);
  x += __shfl_xor(x, 4);
  x += __shfl_xor(x, 8);
  x += __shfl_xor(x, 16);
  x += __shfl_xor(x, 32);
  return x;
}

__device__ __forceinline__ float sigmoid_f(float x) {
  return __builtin_amdgcn_rcpf(1.f + __expf(-x));
}
__device__ __forceinline__ float tanh_f(float x) {
  return 1.f - 2.f * __builtin_amdgcn_rcpf(1.f + __expf(2.f * x));
}

// agent-scope sc1 helpers for the mutable h buffers
__device__ __forceinline__ u64 ld_agent_u64(const float* p) {
  return __hip_atomic_load((const u64*)p, __ATOMIC_RELAXED,
                           __HIP_MEMORY_SCOPE_AGENT);
}
__device__ __forceinline__ void st_agent_f32(float* p, float v) {
  __hip_atomic_store(p, v, __ATOMIC_RELAXED, __HIP_MEMORY_SCOPE_AGENT);
}

__global__ void __launch_bounds__(NTHR, 1) lstm_init_kernel(float* ws) {
  const size_t idx = (size_t)blockIdx.x * blockDim.x + threadIdx.x;
  if (idx < kBarFloats) ((unsigned*)ws)[idx] = 0u;
  if (idx < (size_t)kB * kH) {
    ws[kH1Off + idx] = 0.f;             // h1 state at t=0
    ws[kH2Off + idx] = 0.f;             // h2 slot 0 (t=0)
  }
}

__global__ void __launch_bounds__(NTHR, 1) lstm_persist_kernel(
    const float* __restrict__ x,
    const float* __restrict__ Wih0, const float* __restrict__ Whh0,
    const float* __restrict__ bih0, const float* __restrict__ bhh0,
    const float* __restrict__ Wih1, const float* __restrict__ Whh1,
    const float* __restrict__ bih1, const float* __restrict__ bhh1,
    const float* __restrict__ Wfc, const float* __restrict__ bfc,
    float* __restrict__ out, float* __restrict__ ws) {
  const int tid = threadIdx.x;
  const int bk = blockIdx.x;
  const int w = tid >> 6;               // wave 0..3
  const int lane = tid & 63;
  const int jw = bk * 4 + w;            // owned hidden unit (0..1023)
  unsigned* flags = (unsigned*)ws;
  float* h1 = ws + kH1Off;              // [T+1][B][H]
  float* h2 = ws + kH2Off;              // [2][B][H]
  extern __shared__ float lds[];        // [0..32767] stage, [32768..] Wfc

  // ======================= Phase 0: layer 0 =======================
  {
    float wih[4][4], whh[4][16], bias[4];
#pragma unroll
    for (int g = 0; g < 4; ++g) {
#pragma unroll
      for (int c = 0; c < 4; ++c)
        wih[g][c] = Wih0[(size_t)(g * kH + jw) * kI + c * 64 + lane];
#pragma unroll
      for (int c = 0; c < 16; ++c)
        whh[g][c] = Whh0[(size_t)(g * kH + jw) * kH + c * 64 + lane];
      bias[g] = bih0[g * kH + jw] + bhh0[g * kH + jw];
    }
    float creg = 0.f;                   // c for (b=lane, jw), lanes 0..31

    for (int t = 0; t < kSteps; ++t) {
      // stage h1[t] (128 KB) into LDS: 64 in-flight 8B sc1 loads per thread
      {
        const float* src = h1 + (size_t)t * (kB * kH);
        u64 stmp[64];
#pragma unroll
        for (int i = 0; i < 64; ++i)
          stmp[i] = ld_agent_u64(src + (i * NTHR + tid) * 2);
        u64* d8 = (u64*)lds;
#pragma unroll
        for (int i = 0; i < 64; ++i)
          d8[i * NTHR + tid] = stmp[i];
      }
      __syncthreads();

      float myg0 = 0.f, myg1 = 0.f, myg2 = 0.f, myg3 = 0.f;
      float xv0, xv1, xv2, xv3;
      {
        const float* xp = x + (size_t)t * kI + lane;   // b=0 (read-only: plain)
        xv0 = xp[0]; xv1 = xp[64]; xv2 = xp[128]; xv3 = xp[192];
      }
      for (int b = 0; b < kB; ++b) {
        float a0 = 0.f, a1 = 0.f, a2 = 0.f, a3 = 0.f;
#pragma unroll
        for (int c = 0; c < 16; ++c) {
          const float hv = lds[b * kH + c * 64 + lane];
          a0 = fmaf(hv, whh[0][c], a0);
          a1 = fmaf(hv, whh[1][c], a1);
          a2 = fmaf(hv, whh[2][c], a2);
          a3 = fmaf(hv, whh[3][c], a3);
        }
        float nx0 = 0.f, nx1 = 0.f, nx2 = 0.f, nx3 = 0.f;
        if (b + 1 < kB) {
          const float* xp = x + ((size_t)(b + 1) * kT + t) * kI + lane;
          nx0 = xp[0]; nx1 = xp[64]; nx2 = xp[128]; nx3 = xp[192];
        }
        a0 = fmaf(xv0, wih[0][0], fmaf(xv1, wih[0][1],
             fmaf(xv2, wih[0][2], fmaf(xv3, wih[0][3], a0))));
        a1 = fmaf(xv0, wih[1][0], fmaf(xv1, wih[1][1],
             fmaf(xv2, wih[1][2], fmaf(xv3, wih[1][3], a1))));
        a2 = fmaf(xv0, wih[2][0], fmaf(xv1, wih[2][1],
             fmaf(xv2, wih[2][2], fmaf(xv3, wih[2][3], a2))));
        a3 = fmaf(xv0, wih[3][0], fmaf(xv1, wih[3][1],
             fmaf(xv2, wih[3][2], fmaf(xv3, wih[3][3], a3))));
        xv0 = nx0; xv1 = nx1; xv2 = nx2; xv3 = nx3;
        a0 = wave_sum(a0); a1 = wave_sum(a1);
        a2 = wave_sum(a2); a3 = wave_sum(a3);
        if (lane == b) { myg0 = a0; myg1 = a1; myg2 = a2; myg3 = a3; }
      }
      const float gi = sigmoid_f(myg0 + bias[0]);
      const float gf = sigmoid_f(myg1 + bias[1]);
      const float gg = tanh_f(myg2 + bias[2]);
      const float go = sigmoid_f(myg3 + bias[3]);
      creg = gf * creg + gi * gg;
      const float hnew = go * tanh_f(creg);
      if (lane < kB)
        st_agent_f32(&h1[((size_t)(t + 1) * kB + lane) * kH + jw], hnew);
      grid_barrier(flags, (unsigned)(t + 1));
    }
  }

  // ================= Phase 1: layer 1 + fused FC =================
  {
    float wih[4][16], whh[4][16], bias[4];
#pragma unroll
    for (int g = 0; g < 4; ++g) {
#pragma unroll
      for (int c = 0; c < 16; ++c) {
        wih[g][c] = Wih1[(size_t)(g * kH + jw) * kH + c * 64 + lane];
        whh[g][c] = Whh1[(size_t)(g * kH + jw) * kH + c * 64 + lane];
      }
      bias[g] = bih1[g * kH + jw] + bhh1[g * kH + jw];
    }
    for (int i = tid; i < 2 * kH; i += NTHR)
      lds[32768 + i] = Wfc[(size_t)(bk * 2) * kH + i];
    const int o_loc = w & 1;
    const int b_sub = (w >> 1) * 8;
    const float bfco = bfc[bk * 2 + o_loc];
    float creg = 0.f;

    for (int t = 0; t < kSteps; ++t) {
      float myg0 = 0.f, myg1 = 0.f, myg2 = 0.f, myg3 = 0.f;
      for (int grp = 0; grp < 2; ++grp) {
        __syncthreads();                // previous group's reads done
        {
          const float* s1 = h1 + ((size_t)(t + 1) * kB + grp * 16) * kH;
          const float* s2 = h2 + ((size_t)(t & 1) * kB + grp * 16) * kH;
          u64 t1[32], t2[32];
#pragma unroll
          for (int i = 0; i < 32; ++i) {
            t1[i] = ld_agent_u64(s1 + (i * NTHR + tid) * 2);
            t2[i] = ld_agent_u64(s2 + (i * NTHR + tid) * 2);
          }
          u64* d1 = (u64*)lds;
          u64* d2 = (u64*)(lds + 16384);
#pragma unroll
          for (int i = 0; i < 32; ++i) {
            d1[i * NTHR + tid] = t1[i];
            d2[i * NTHR + tid] = t2[i];
          }
        }
        __syncthreads();
        for (int b2 = 0; b2 < 16; ++b2) {
          const int b = grp * 16 + b2;
          float a0 = 0.f, a1 = 0.f, a2 = 0.f, a3 = 0.f;
#pragma unroll
          for (int c = 0; c < 16; ++c) {          // input part: h1[t+1]
            const float hv = lds[b2 * kH + c * 64 + lane];
            a0 = fmaf(hv, wih[0][c], a0);
            a1 = fmaf(hv, wih[1][c], a1);
            a2 = fmaf(hv, wih[2][c], a2);
            a3 = fmaf(hv, wih[3][c], a3);
          }
#pragma unroll
          for (int c = 0; c < 16; ++c) {          // recurrent part: h2[t]
            const float gv = lds[16384 + b2 * kH + c * 64 + lane];
            a0 = fmaf(gv, whh[0][c], a0);
            a1 = fmaf(gv, whh[1][c], a1);
            a2 = fmaf(gv, whh[2][c], a2);
            a3 = fmaf(gv, whh[3][c], a3);
          }
          a0 = wave_sum(a0); a1 = wave_sum(a1);
          a2 = wave_sum(a2); a3 = wave_sum(a3);
          if (lane == b) { myg0 = a0; myg1 = a1; myg2 = a2; myg3 = a3; }
        }
        // fused FC on staged h2[t] (= layer-2 output at time t-1)
        if (t >= 1 && t <= kTR) {
          float wf[16];
#pragma unroll
          for (int c = 0; c < 16; ++c)
            wf[c] = lds[32768 + o_loc * kH + c * 64 + lane];
          float myout = 0.f;
          for (int b2 = 0; b2 < 8; ++b2) {
            const int bb = b_sub + b2;
            float f = 0.f;
#pragma unroll
            for (int c = 0; c < 16; ++c)
              f = fmaf(lds[16384 + bb * kH + c * 64 + lane], wf[c], f);
            f = wave_sum(f);
            if (lane == b2) myout = f;
          }
          if (lane < 8) {
            const int b = grp * 16 + b_sub + lane;
            out[((size_t)b * kTR + (t - 1)) * kO + bk * 2 + o_loc] =
                myout + bfco;
          }
        }
      }
      const float gi = sigmoid_f(myg0 + bias[0]);
      const float gf = sigmoid_f(myg1 + bias[1]);
      const float gg = tanh_f(myg2 + bias[2]);
      const float go = sigmoid_f(myg3 + bias[3]);
      creg = gf * creg + gi * gg;
      const float hnew = go * tanh_f(creg);
      if (lane < kB)
        st_agent_f32(&h2[((size_t)((t + 1) & 1) * kB + lane) * kH + jw], hnew);
      if (t + 1 < kSteps)                      // last barrier not needed
        grid_barrier(flags, (unsigned)(kSteps + t + 1));
    }
  }
}

extern "C" void kernel_launch(void* const* d_in, const int* in_sizes, int n_in,
                              void* d_out, int out_size, void* d_ws,
                              size_t ws_size, hipStream_t stream) {
  const float* x    = (const float*)d_in[0];
  const float* Wih0 = (const float*)d_in[1];
  const float* Whh0 = (const float*)d_in[2];
  const float* bih0 = (const float*)d_in[3];
  const float* bhh0 = (const float*)d_in[4];
  const float* Wih1 = (const float*)d_in[5];
  const float* Whh1 = (const float*)d_in[6];
  const float* bih1 = (const float*)d_in[7];
  const float* bhh1 = (const float*)d_in[8];
  const float* Wfc  = (const float*)d_in[9];
  const float* bfc  = (const float*)d_in[10];
  float* out = (float*)d_out;
  float* ws  = (float*)d_ws;

  (void)hipFuncSetAttribute((const void*)lstm_persist_kernel,
                            hipFuncAttributeMaxDynamicSharedMemorySize,
                            kLdsBytes);

  hipLaunchKernelGGL(lstm_init_kernel, dim3(128), dim3(NTHR), 0, stream, ws);
  hipLaunchKernelGGL(lstm_persist_kernel, dim3(NBLK), dim3(NTHR), kLdsBytes,
                     stream, x, Wih0, Whh0, bih0, bhh0, Wih1, Whh1, bih1,
                     bhh1, Wfc, bfc, out, ws);
}

// Round 3
// 25929.434 us; speedup vs baseline: 1.9124x; 1.0947x over previous
//
#include <hip/hip_runtime.h>
#include <cstdint>
#include <cstddef>

// ============================================================================
// Persistent fused 2-layer LSTM + FC for MI355X (gfx950) — Round 3.
// R2 post-mortem: 1 wave/SIMD, 1001 barriers, shuffle-chain latency and
// 4KB-stride h-scatter (9x HBM write amplification) left ~80% of each step
// as dead latency. R3 restructures:
//   - 512 thr/block (8 waves, 2/SIMD) for TLP latency hiding.
//   - Layer-pipelined: blocks 0-127 = layer 0 (round r), blocks 128-255 =
//     layer 1 + fused FC (round r, one step behind). 501 barriers vs 1001.
//   - h layout [t][j][b]: each wave's h-store is one contiguous 128B line.
//     LDS staging transposes to [k][b] (stride 33 / 17: conflict-free).
//   - Merged 4-gate butterfly reduction (23 ops vs 48) + LDS gate exchange.
//   - FC fused into the recurrent c-loop (Wfc held in 16 VGPRs).
// ============================================================================

#define NBLK 256
#define NTHR 512

namespace {
constexpr int kB = 32, kT = 512, kI = 256, kH = 1024, kO = 512, kTR = 500;
constexpr int kRounds = 502;                 // r = 0..501
// workspace layout (floats):
constexpr size_t kBarFloats = 2048;          // flags[256] + gen word
constexpr size_t kH1Off = kBarFloats;        // h1_state[502][1024][32]
constexpr size_t kH1Len = (size_t)kRounds * kH * kB;
constexpr size_t kH2Off = kH1Off + kH1Len;   // h2_state[2][1024][32]
// LDS (floats): L0: stage[1024*33]=33792 | L1: 2 x stage[1024*17]=34816
constexpr int kXchg = 34816;                 // gate-exchange region (1024 f)
constexpr int kLdsFloats = kXchg + 1024;
constexpr int kLdsBytes = kLdsFloats * 4;    // 143360 B -> 1 block/CU
constexpr int kGenWord = 320;
}

typedef unsigned long long u64;

// ---------------------------------------------------------------------------
// Grid barrier (monotonic step numbers 1..501): parallel flag stores + one
// sweeper wave in block 0; no fences (all shared data moves via sc1 atomics).
// ---------------------------------------------------------------------------
__device__ __forceinline__ void grid_barrier(unsigned* flags, unsigned step) {
  __syncthreads();                      // all waves' stores drained (vmcnt)
  const int tid = threadIdx.x;
  if (blockIdx.x == 0) {
    if (tid < 64) {
      if (tid == 0)
        __hip_atomic_store(&flags[0], step, __ATOMIC_RELEASE,
                           __HIP_MEMORY_SCOPE_AGENT);
      const int l4 = tid << 2;
      bool done;
      do {
        unsigned ok = 1u;
#pragma unroll
        for (int k = 0; k < 4; ++k)
          ok &= (unsigned)(__hip_atomic_load(&flags[l4 + k], __ATOMIC_RELAXED,
                                             __HIP_MEMORY_SCOPE_AGENT) >= step);
        done = __all((int)ok);
        if (!done) __builtin_amdgcn_s_sleep(1);
      } while (!done);
      if (tid == 0)
        __hip_atomic_store(&flags[kGenWord], step, __ATOMIC_RELEASE,
                           __HIP_MEMORY_SCOPE_AGENT);
    }
  } else if (tid == 0) {
    __hip_atomic_store(&flags[blockIdx.x], step, __ATOMIC_RELEASE,
                       __HIP_MEMORY_SCOPE_AGENT);
    while (__hip_atomic_load(&flags[kGenWord], __ATOMIC_RELAXED,
                             __HIP_MEMORY_SCOPE_AGENT) < step)
      __builtin_amdgcn_s_sleep(2);
  }
  if (tid == 0)
    (void)__hip_atomic_load(&flags[kGenWord], __ATOMIC_ACQUIRE,
                            __HIP_MEMORY_SCOPE_AGENT);
  __syncthreads();
}

// Merged 4-value butterfly: returns total of a_{lane%4} in every lane.
__device__ __forceinline__ float merged_gate_reduce(float a0, float a1,
                                                    float a2, float a3,
                                                    int lane) {
  a0 += __shfl_xor(a0, 1); a1 += __shfl_xor(a1, 1);
  a2 += __shfl_xor(a2, 1); a3 += __shfl_xor(a3, 1);
  float v0 = (lane & 1) ? a1 : a0;
  float v1 = (lane & 1) ? a3 : a2;
  v0 += __shfl_xor(v0, 2); v1 += __shfl_xor(v1, 2);
  float u = (lane & 2) ? v1 : v0;
  u += __shfl_xor(u, 4);
  u += __shfl_xor(u, 8);
  u += __shfl_xor(u, 16);
  u += __shfl_xor(u, 32);
  return u;
}

__device__ __forceinline__ float wave_sum(float x) {
  x += __shfl_xor(x, 1);  x += __shfl_xor(x, 2);
  x += __shfl_xor(x, 4);  x += __shfl_xor(x, 8);
  x += __shfl_xor(x, 16); x += __shfl_xor(x, 32);
  return x;
}

__device__ __forceinline__ float sigmoid_f(float x) {
  return __builtin_amdgcn_rcpf(1.f + __expf(-x));
}
__device__ __forceinline__ float tanh_f(float x) {
  return 1.f - 2.f * __builtin_amdgcn_rcpf(1.f + __expf(2.f * x));
}

// agent-scope sc1 helpers for the mutable h buffers
__device__ __forceinline__ u64 ld_agent_u64(const float* p) {
  return __hip_atomic_load((const u64*)p, __ATOMIC_RELAXED,
                           __HIP_MEMORY_SCOPE_AGENT);
}
__device__ __forceinline__ void st_agent_f32(float* p, float v) {
  __hip_atomic_store(p, v, __ATOMIC_RELAXED, __HIP_MEMORY_SCOPE_AGENT);
}
__device__ __forceinline__ float u64_lo(u64 v) {
  return __uint_as_float((unsigned)(v & 0xffffffffull));
}
__device__ __forceinline__ float u64_hi(u64 v) {
  return __uint_as_float((unsigned)(v >> 32));
}

__global__ void __launch_bounds__(256, 1) lstm_init_kernel(float* ws) {
  const size_t idx = (size_t)blockIdx.x * blockDim.x + threadIdx.x;
  if (idx < kBarFloats) ((unsigned*)ws)[idx] = 0u;
  if (idx < (size_t)kB * kH) {
    ws[kH1Off + idx] = 0.f;             // h1_state[0] = 0
    ws[kH2Off + idx] = 0.f;             // h2_state slot 0 = 0
  }
}

__global__ void __launch_bounds__(NTHR, 2) lstm_persist_kernel(
    const float* __restrict__ x,
    const float* __restrict__ Wih0, const float* __restrict__ Whh0,
    const float* __restrict__ bih0, const float* __restrict__ bhh0,
    const float* __restrict__ Wih1, const float* __restrict__ Whh1,
    const float* __restrict__ bih1, const float* __restrict__ bhh1,
    const float* __restrict__ Wfc, const float* __restrict__ bfc,
    float* __restrict__ out, float* __restrict__ ws) {
  const int tid = threadIdx.x;
  const int bk = blockIdx.x;
  const int w = tid >> 6;               // wave 0..7
  const int lane = tid & 63;
  unsigned* flags = (unsigned*)ws;
  float* h1s = ws + kH1Off;             // [502][1024][32]
  float* h2s = ws + kH2Off;             // [2][1024][32]
  extern __shared__ float lds[];

  if (bk < 128) {
    // ========================= Layer 0 =========================
    const int j0 = bk * 8 + w;          // owned hidden unit
    float whh[4][16], wih[4][4], bias[4];
#pragma unroll
    for (int g = 0; g < 4; ++g) {
#pragma unroll
      for (int c = 0; c < 16; ++c)
        whh[g][c] = Whh0[(size_t)(g * kH + j0) * kH + c * 64 + lane];
#pragma unroll
      for (int c = 0; c < 4; ++c)
        wih[g][c] = Wih0[(size_t)(g * kH + j0) * kI + c * 64 + lane];
      bias[g] = bih0[g * kH + j0] + bhh0[g * kH + j0];
    }
    float creg = 0.f;                   // c for (b=lane, j0), lanes 0..31

    for (int r = 0; r <= 500; ++r) {
      // stage h1_state[r] ([j][b] global) -> lds [k][b], stride 33
      {
        const float* src = h1s + (size_t)r * (kH * kB);
        u64 tbuf[32];
#pragma unroll
        for (int i = 0; i < 32; ++i)
          tbuf[i] = ld_agent_u64(src + (size_t)(i * NTHR + tid) * 2);
        __syncthreads();                // prior-round LDS reads complete
#pragma unroll
        for (int i = 0; i < 32; ++i) {
          const int idx = i * NTHR + tid;
          const int j = idx >> 4, q = (idx & 15) * 2;
          lds[j * 33 + q]     = u64_lo(tbuf[i]);
          lds[j * 33 + q + 1] = u64_hi(tbuf[i]);
        }
      }
      __syncthreads();

      float xv0, xv1, xv2, xv3;
      {
        const float* xp = x + (size_t)r * kI + lane;     // b=0
        xv0 = xp[0]; xv1 = xp[64]; xv2 = xp[128]; xv3 = xp[192];
      }
      for (int b = 0; b < kB; ++b) {
        float a0 = 0.f, a1 = 0.f, a2 = 0.f, a3 = 0.f;
#pragma unroll
        for (int c = 0; c < 16; ++c) {
          const float hv = lds[(c * 64 + lane) * 33 + b];
          a0 = fmaf(hv, whh[0][c], a0);
          a1 = fmaf(hv, whh[1][c], a1);
          a2 = fmaf(hv, whh[2][c], a2);
          a3 = fmaf(hv, whh[3][c], a3);
        }
        float nx0 = 0.f, nx1 = 0.f, nx2 = 0.f, nx3 = 0.f;
        if (b + 1 < kB) {
          const float* xp = x + ((size_t)(b + 1) * kT + r) * kI + lane;
          nx0 = xp[0]; nx1 = xp[64]; nx2 = xp[128]; nx3 = xp[192];
        }
        a0 = fmaf(xv0, wih[0][0], fmaf(xv1, wih[0][1],
             fmaf(xv2, wih[0][2], fmaf(xv3, wih[0][3], a0))));
        a1 = fmaf(xv0, wih[1][0], fmaf(xv1, wih[1][1],
             fmaf(xv2, wih[1][2], fmaf(xv3, wih[1][3], a1))));
        a2 = fmaf(xv0, wih[2][0], fmaf(xv1, wih[2][1],
             fmaf(xv2, wih[2][2], fmaf(xv3, wih[2][3], a2))));
        a3 = fmaf(xv0, wih[3][0], fmaf(xv1, wih[3][1],
             fmaf(xv2, wih[3][2], fmaf(xv3, wih[3][3], a3))));
        xv0 = nx0; xv1 = nx1; xv2 = nx2; xv3 = nx3;
        const float u = merged_gate_reduce(a0, a1, a2, a3, lane);
        if (lane < 4) lds[kXchg + w * 128 + b * 4 + lane] = u;
      }
      if (lane < 32) {                  // gate math for batch b=lane
        const float4 g4 =
            *(const float4*)&lds[kXchg + w * 128 + lane * 4];
        const float gi = sigmoid_f(g4.x + bias[0]);
        const float gf = sigmoid_f(g4.y + bias[1]);
        const float gg = tanh_f(g4.z + bias[2]);
        const float go = sigmoid_f(g4.w + bias[3]);
        creg = gf * creg + gi * gg;
        const float hnew = go * tanh_f(creg);
        // one contiguous 128B line per wave
        st_agent_f32(&h1s[(size_t)(r + 1) * (kH * kB) + j0 * kB + lane],
                     hnew);
      }
      grid_barrier(flags, (unsigned)(r + 1));
    }
  } else {
    // ==================== Layer 1 + fused FC ====================
    const int bl = bk - 128;
    const int j1 = bl * 8 + w;
    float wih[4][16], whh[4][16], bias[4], wfc[16];
#pragma unroll
    for (int g = 0; g < 4; ++g) {
#pragma unroll
      for (int c = 0; c < 16; ++c) {
        wih[g][c] = Wih1[(size_t)(g * kH + j1) * kH + c * 64 + lane];
        whh[g][c] = Whh1[(size_t)(g * kH + j1) * kH + c * 64 + lane];
      }
      bias[g] = bih1[g * kH + j1] + bhh1[g * kH + j1];
    }
    const bool fcw = (w < 4);           // waves 0-3 own FC col bl*4+w
    float bfco = 0.f;
#pragma unroll
    for (int c = 0; c < 16; ++c)
      wfc[c] = fcw ? Wfc[(size_t)(bl * 4 + w) * kH + c * 64 + lane] : 0.f;
    if (fcw) bfco = bfc[bl * 4 + w];
    float creg0 = 0.f, creg1 = 0.f;     // c for b=lane(half0), b=16+lane
    float* ldsH1 = lds;                 // [k][b-half], stride 17
    float* ldsH2 = lds + 17408;

    grid_barrier(flags, 1u);            // round 0: no L1 work
    for (int r = 1; r <= 501; ++r) {
      const float* s1 = h1s + (size_t)r * (kH * kB);
      const float* s2 = h2s + (size_t)((r - 1) & 1) * (kH * kB);
#pragma unroll
      for (int half = 0; half < 2; ++half) {
        {
          u64 t1[16], t2[16];
#pragma unroll
          for (int i = 0; i < 16; ++i) {
            const int idx = i * NTHR + tid;
            const int j = idx >> 3, q = (idx & 7) * 2;
            t1[i] = ld_agent_u64(s1 + j * kB + half * 16 + q);
            t2[i] = ld_agent_u64(s2 + j * kB + half * 16 + q);
          }
          __syncthreads();              // previous compute's LDS reads done
#pragma unroll
          for (int i = 0; i < 16; ++i) {
            const int idx = i * NTHR + tid;
            const int j = idx >> 3, q = (idx & 7) * 2;
            ldsH1[j * 17 + q]     = u64_lo(t1[i]);
            ldsH1[j * 17 + q + 1] = u64_hi(t1[i]);
            ldsH2[j * 17 + q]     = u64_lo(t2[i]);
            ldsH2[j * 17 + q + 1] = u64_hi(t2[i]);
          }
        }
        __syncthreads();
        float myfc = 0.f;
        for (int b2 = 0; b2 < 16; ++b2) {
          float a0 = 0.f, a1 = 0.f, a2 = 0.f, a3 = 0.f, a4 = 0.f;
#pragma unroll
          for (int c = 0; c < 16; ++c) {          // input part: h1[r]
            const float hv = ldsH1[(c * 64 + lane) * 17 + b2];
            a0 = fmaf(hv, wih[0][c], a0);
            a1 = fmaf(hv, wih[1][c], a1);
            a2 = fmaf(hv, wih[2][c], a2);
            a3 = fmaf(hv, wih[3][c], a3);
          }
#pragma unroll
          for (int c = 0; c < 16; ++c) {          // recurrent: h2[r-1]
            const float gv = ldsH2[(c * 64 + lane) * 17 + b2];
            a0 = fmaf(gv, whh[0][c], a0);
            a1 = fmaf(gv, whh[1][c], a1);
            a2 = fmaf(gv, whh[2][c], a2);
            a3 = fmaf(gv, whh[3][c], a3);
            if (fcw) a4 = fmaf(gv, wfc[c], a4);   // fused FC on h2[r-1]
          }
          const float u = merged_gate_reduce(a0, a1, a2, a3, lane);
          if (lane < 4) lds[kXchg + w * 64 + b2 * 4 + lane] = u;
          if (fcw) {
            a4 = wave_sum(a4);
            if (lane == b2) myfc = a4;
          }
        }
        if (lane < 16) {                // gate math for b = half*16+lane
          const float4 g4 =
              *(const float4*)&lds[kXchg + w * 64 + lane * 4];
          const float gi = sigmoid_f(g4.x + bias[0]);
          const float gf = sigmoid_f(g4.y + bias[1]);
          const float gg = tanh_f(g4.z + bias[2]);
          const float go = sigmoid_f(g4.w + bias[3]);
          float cr = half ? creg1 : creg0;
          cr = gf * cr + gi * gg;
          if (half) creg1 = cr; else creg0 = cr;
          const float hnew = go * tanh_f(cr);
          st_agent_f32(&h2s[(size_t)(r & 1) * (kH * kB) + j1 * kB +
                            half * 16 + lane], hnew);
        }
        if (fcw && r >= 2 && lane < 16) {
          const int b = half * 16 + lane;
          out[((size_t)b * kTR + (r - 2)) * kO + bl * 4 + w] = myfc + bfco;
        }
      }
      if (r <= 500) grid_barrier(flags, (unsigned)(r + 1));
    }
  }
}

extern "C" void kernel_launch(void* const* d_in, const int* in_sizes, int n_in,
                              void* d_out, int out_size, void* d_ws,
                              size_t ws_size, hipStream_t stream) {
  const float* x    = (const float*)d_in[0];
  const float* Wih0 = (const float*)d_in[1];
  const float* Whh0 = (const float*)d_in[2];
  const float* bih0 = (const float*)d_in[3];
  const float* bhh0 = (const float*)d_in[4];
  const float* Wih1 = (const float*)d_in[5];
  const float* Whh1 = (const float*)d_in[6];
  const float* bih1 = (const float*)d_in[7];
  const float* bhh1 = (const float*)d_in[8];
  const float* Wfc  = (const float*)d_in[9];
  const float* bfc  = (const float*)d_in[10];
  float* out = (float*)d_out;
  float* ws  = (float*)d_ws;

  (void)hipFuncSetAttribute((const void*)lstm_persist_kernel,
                            hipFuncAttributeMaxDynamicSharedMemorySize,
                            kLdsBytes);

  hipLaunchKernelGGL(lstm_init_kernel, dim3(128), dim3(256), 0, stream, ws);
  hipLaunchKernelGGL(lstm_persist_kernel, dim3(NBLK), dim3(NTHR), kLdsBytes,
                     stream, x, Wih0, Whh0, bih0, bhh0, Wih1, Whh1, bih1,
                     bhh1, Wfc, bfc, out, ws);
}